// Round 1
// baseline (854.601 us; speedup 1.0000x reference)
//
#include <hip/hip_runtime.h>
#include <cstdint>
#include <cstddef>

#define B_ 16384
#define K_ 512
#define H_ 4096
#define O_ 512

#define BM 128
#define BN 128
#define BKK 16

// Replicates numpy pairwise_sum order for sum(a*a) over 512 contiguous floats:
// 512 -> 256+256 -> (128+128)+(128+128); each 128-block uses the 8-accumulator
// unrolled loop, combined as ((r0+r1)+(r2+r3))+((r4+r5)+(r6+r7)).
// __fmul_rn/__fadd_rn prevent FMA contraction (numpy squares then adds, unfused).
__device__ float np_pairwise_sumsq512(const float* __restrict__ a) {
  float s[4];
  #pragma unroll
  for (int blk = 0; blk < 4; ++blk) {
    const float* p = a + blk * 128;
    float r[8];
    #pragma unroll
    for (int j = 0; j < 8; ++j) r[j] = __fmul_rn(p[j], p[j]);
    for (int i = 8; i < 128; i += 8) {
      #pragma unroll
      for (int j = 0; j < 8; ++j) r[j] = __fadd_rn(r[j], __fmul_rn(p[i + j], p[i + j]));
    }
    s[blk] = __fadd_rn(__fadd_rn(__fadd_rn(r[0], r[1]), __fadd_rn(r[2], r[3])),
                       __fadd_rn(__fadd_rn(r[4], r[5]), __fadd_rn(r[6], r[7])));
  }
  return __fadd_rn(__fadd_rn(s[0], s[1]), __fadd_rn(s[2], s[3]));
}

__global__ void rowsumsq_kernel(const float* __restrict__ src, float* __restrict__ dst,
                                int nrows) {
  int r = blockIdx.x * blockDim.x + threadIdx.x;
  if (r < nrows) dst[r] = np_pairwise_sumsq512(src + (size_t)r * K_);
}

__global__ void init_keys_kernel(unsigned long long* __restrict__ keys) {
  int i = blockIdx.x * blockDim.x + threadIdx.x;
  if (i < B_) keys[i] = 0xFFFFFFFFFFFFFFFFULL;
}

// G [O_][H_] -> GT [H_][O_]
__global__ void transposeG_kernel(const float* __restrict__ G, float* __restrict__ GT) {
  __shared__ float t[32][33];
  int h0 = blockIdx.x * 32, o0 = blockIdx.y * 32;
  for (int i = threadIdx.y; i < 32; i += 8)
    t[i][threadIdx.x] = G[(size_t)(o0 + i) * H_ + h0 + threadIdx.x];
  __syncthreads();
  for (int i = threadIdx.y; i < 32; i += 8)
    GT[(size_t)(h0 + i) * O_ + o0 + threadIdx.x] = t[threadIdx.x][i];
}

// Fused distance + per-row argmin. 128x128 tile, BK=16, 256 threads, 8x8 acc.
// Dot product: strict ascending-k single-accumulator FMA chain (matches BLAS sgemm).
__global__ __launch_bounds__(256) void dist_argmin_kernel(
    const float* __restrict__ x, const float* __restrict__ W,
    const float* __restrict__ xsq, const float* __restrict__ wsq,
    unsigned long long* __restrict__ keys) {
  __shared__ float xs[BKK][BM + 4];
  __shared__ float wsh[BKK][BN + 4];
  const int row0 = blockIdx.x * BM;
  const int col0 = blockIdx.y * BN;
  const int tid = (int)threadIdx.x;
  const int tx = tid & 15, ty = tid >> 4;

  float acc[8][8];
  #pragma unroll
  for (int i = 0; i < 8; ++i)
    #pragma unroll
    for (int j = 0; j < 8; ++j) acc[i][j] = 0.0f;

  for (int kt = 0; kt < K_; kt += BKK) {
    #pragma unroll
    for (int l = 0; l < 2; ++l) {
      int e = tid + l * 256;          // 0..511 -> covers 128 rows x 4 float4s
      int r = e >> 2, kq = e & 3;
      float4 v = *(const float4*)(x + (size_t)(row0 + r) * K_ + kt + kq * 4);
      xs[kq * 4 + 0][r] = v.x;
      xs[kq * 4 + 1][r] = v.y;
      xs[kq * 4 + 2][r] = v.z;
      xs[kq * 4 + 3][r] = v.w;
      float4 u = *(const float4*)(W + (size_t)(col0 + r) * K_ + kt + kq * 4);
      wsh[kq * 4 + 0][r] = u.x;
      wsh[kq * 4 + 1][r] = u.y;
      wsh[kq * 4 + 2][r] = u.z;
      wsh[kq * 4 + 3][r] = u.w;
    }
    __syncthreads();
    #pragma unroll
    for (int k = 0; k < BKK; ++k) {
      float4 a0 = *(const float4*)&xs[k][ty * 4];
      float4 a1 = *(const float4*)&xs[k][ty * 4 + 64];
      float4 b0 = *(const float4*)&wsh[k][tx * 4];
      float4 b1 = *(const float4*)&wsh[k][tx * 4 + 64];
      float ar[8] = {a0.x, a0.y, a0.z, a0.w, a1.x, a1.y, a1.z, a1.w};
      float br[8] = {b0.x, b0.y, b0.z, b0.w, b1.x, b1.y, b1.z, b1.w};
      #pragma unroll
      for (int i = 0; i < 8; ++i)
        #pragma unroll
        for (int j = 0; j < 8; ++j)
          acc[i][j] = fmaf(ar[i], br[j], acc[i][j]);
    }
    __syncthreads();
  }

  // Epilogue: dist = sqrt(max((x_sq - 2*dot) + w_sq, 0)); argmin with
  // first-index tie-break via (dist_bits, h) lexicographic min.
  float xv[8], wv[8];
  int rowidx[8], colidx[8];
  #pragma unroll
  for (int i = 0; i < 8; ++i) {
    rowidx[i] = row0 + ty * 4 + (i & 3) + (i >> 2) * 64;
    xv[i] = xsq[rowidx[i]];
  }
  #pragma unroll
  for (int j = 0; j < 8; ++j) {
    colidx[j] = col0 + tx * 4 + (j & 3) + (j >> 2) * 64;
    wv[j] = wsq[colidx[j]];
  }
  #pragma unroll
  for (int i = 0; i < 8; ++i) {
    unsigned long long best = 0xFFFFFFFFFFFFFFFFULL;
    #pragma unroll
    for (int j = 0; j < 8; ++j) {
      float t2 = xv[i] - 2.0f * acc[i][j];   // np order: x_sq - 2*m  (2*dot exact)
      float sq = t2 + wv[j];                 // ... + w_sq
      float d = sqrtf(fmaxf(sq, 0.0f));      // correctly-rounded sqrt, d >= 0
      unsigned long long key =
          ((unsigned long long)__float_as_uint(d) << 32) | (unsigned)colidx[j];
      best = key < best ? key : best;
    }
    #pragma unroll
    for (int off = 1; off < 16; off <<= 1) {
      unsigned long long o = __shfl_xor(best, off, 16);
      best = o < best ? o : best;
    }
    if (tx == 0) atomicMin(&keys[rowidx[i]], best);
  }
}

__global__ void finalize_kernel(const unsigned long long* __restrict__ keys,
                                const float* __restrict__ GT,
                                const float* __restrict__ G,
                                float* __restrict__ out, int useGT) {
  int b = blockIdx.x;
  unsigned h = (unsigned)(keys[b] & 0xFFFFFFFFULL);
  if (threadIdx.x == 0) out[(size_t)B_ * O_ + b] = (float)h;
  if (useGT) {
    const float4* src = (const float4*)(GT + (size_t)h * O_);
    float4* dst = (float4*)(out + (size_t)b * O_);
    for (int i = threadIdx.x; i < O_ / 4; i += blockDim.x) dst[i] = src[i];
  } else {
    for (int o = threadIdx.x; o < O_; o += blockDim.x)
      out[(size_t)b * O_ + o] = G[(size_t)o * H_ + h];
  }
}

extern "C" void kernel_launch(void* const* d_in, const int* in_sizes, int n_in,
                              void* d_out, int out_size, void* d_ws, size_t ws_size,
                              hipStream_t stream) {
  const float* x = (const float*)d_in[0];
  const float* W = (const float*)d_in[1];
  const float* G = (const float*)d_in[2];
  float* out = (float*)d_out;

  char* ws = (char*)d_ws;
  unsigned long long* keys = (unsigned long long*)ws;             // 16384*8 = 131072 B
  float* xsq = (float*)(ws + 131072);                             // 16384*4 = 65536 B
  float* wsq = (float*)(ws + 131072 + 65536);                     // 4096*4  = 16384 B
  float* GT  = (float*)(ws + 131072 + 65536 + 16384);             // 4096*512*4 = 8 MiB
  size_t base = 131072 + 65536 + 16384;
  int useGT = ws_size >= base + (size_t)H_ * O_ * 4 ? 1 : 0;

  hipLaunchKernelGGL(init_keys_kernel, dim3(B_ / 256), dim3(256), 0, stream, keys);
  hipLaunchKernelGGL(rowsumsq_kernel, dim3(B_ / 256), dim3(256), 0, stream, x, xsq, B_);
  hipLaunchKernelGGL(rowsumsq_kernel, dim3(H_ / 256), dim3(256), 0, stream, W, wsq, H_);
  if (useGT)
    hipLaunchKernelGGL(transposeG_kernel, dim3(H_ / 32, O_ / 32), dim3(32, 8), 0, stream,
                       G, GT);
  hipLaunchKernelGGL(dist_argmin_kernel, dim3(B_ / BM, H_ / BN), dim3(256), 0, stream,
                     x, W, xsq, wsq, keys);
  hipLaunchKernelGGL(finalize_kernel, dim3(B_), dim3(128), 0, stream, keys, GT, G, out,
                     useGT);
}

// Round 2
// 478.883 us; speedup vs baseline: 1.7846x; 1.7846x over previous
//
#include <hip/hip_runtime.h>
#include <cstdint>
#include <cstddef>

#define B_ 16384
#define K_ 512
#define H_ 4096
#define O_ 512

typedef __attribute__((ext_vector_type(4))) float f32x4;
typedef __attribute__((ext_vector_type(8))) short bf16x8;

// ---------------------------------------------------------------------------
// Shared exact helpers (proven bitwise-exact vs numpy reference in round 1)
// ---------------------------------------------------------------------------
__device__ float np_pairwise_sumsq512(const float* __restrict__ a) {
  float s[4];
  #pragma unroll
  for (int blk = 0; blk < 4; ++blk) {
    const float* p = a + blk * 128;
    float r[8];
    #pragma unroll
    for (int j = 0; j < 8; ++j) r[j] = __fmul_rn(p[j], p[j]);
    for (int i = 8; i < 128; i += 8) {
      #pragma unroll
      for (int j = 0; j < 8; ++j) r[j] = __fadd_rn(r[j], __fmul_rn(p[i + j], p[i + j]));
    }
    s[blk] = __fadd_rn(__fadd_rn(__fadd_rn(r[0], r[1]), __fadd_rn(r[2], r[3])),
                       __fadd_rn(__fadd_rn(r[4], r[5]), __fadd_rn(r[6], r[7])));
  }
  return __fadd_rn(__fadd_rn(s[0], s[1]), __fadd_rn(s[2], s[3]));
}

__global__ void rowsumsq_kernel(const float* __restrict__ src, float* __restrict__ dst,
                                int nrows) {
  int r = blockIdx.x * blockDim.x + threadIdx.x;
  if (r < nrows) dst[r] = np_pairwise_sumsq512(src + (size_t)r * K_);
}

// G [O_][H_] -> GT [H_][O_]
__global__ void transposeG_kernel(const float* __restrict__ G, float* __restrict__ GT) {
  __shared__ float t[32][33];
  int h0 = blockIdx.x * 32, o0 = blockIdx.y * 32;
  for (int i = threadIdx.y; i < 32; i += 8)
    t[i][threadIdx.x] = G[(size_t)(o0 + i) * H_ + h0 + threadIdx.x];
  __syncthreads();
  for (int i = threadIdx.y; i < 32; i += 8)
    GT[(size_t)(h0 + i) * O_ + o0 + threadIdx.x] = t[threadIdx.x][i];
}

// ---------------------------------------------------------------------------
// MFMA path: bf16 hi/lo split (3-product), 16-col group minima, exact rescore
// ---------------------------------------------------------------------------
__device__ inline unsigned short f32_to_bf16_rne(float f) {
  unsigned u = __float_as_uint(f);
  unsigned r = (u + 0x7fffu + ((u >> 16) & 1u)) >> 16;
  return (unsigned short)r;
}
__device__ inline float bf16_to_f32(unsigned short h) {
  return __uint_as_float((unsigned)h << 16);
}

__global__ void convert_hilo_kernel(const float* __restrict__ src,
                                    unsigned short* __restrict__ hi,
                                    unsigned short* __restrict__ lo, int n4) {
  int i = blockIdx.x * blockDim.x + threadIdx.x;
  if (i >= n4) return;
  float4 v = ((const float4*)src)[i];
  float f[4] = {v.x, v.y, v.z, v.w};
  ushort4 h, l;
  unsigned short hh[4], ll[4];
  #pragma unroll
  for (int j = 0; j < 4; ++j) {
    unsigned short hb = f32_to_bf16_rne(f[j]);
    float res = f[j] - bf16_to_f32(hb);
    hh[j] = hb;
    ll[j] = f32_to_bf16_rne(res);
  }
  h.x = hh[0]; h.y = hh[1]; h.z = hh[2]; h.w = hh[3];
  l.x = ll[0]; l.y = ll[1]; l.z = ll[2]; l.w = ll[3];
  ((ushort4*)hi)[i] = h;
  ((ushort4*)lo)[i] = l;
}

// stage one [128][32]bf16 tile (8KB) via global_load_lds (16B/lane)
__device__ inline void stage_tile(unsigned short* lds, const unsigned short* src,
                                  int row0, int kb, int wid, int lane) {
  #pragma unroll
  for (int j = 0; j < 2; ++j) {
    int chunk = wid + j * 4;          // 8 x 1KB chunks
    int e = chunk * 64 + lane;        // 16B-unit index, 0..511
    int row = e >> 2, kc = e & 3;
    const char* g = (const char*)src + (size_t)(row0 + row) * (K_ * 2) + kb + kc * 16;
    char* l = (char*)lds + chunk * 1024;
    __builtin_amdgcn_global_load_lds((const __attribute__((address_space(1))) void*)g,
                                     (__attribute__((address_space(3))) void*)l,
                                     16, 0, 0);
  }
}

__device__ inline bf16x8 lds_frag(const unsigned short* lds, int row, int kbyte) {
  return *(const bf16x8*)((const char*)lds + row * 64 + kbyte);
}

// C tile 128x128, BK=32 f32 (=32 bf16 per product), 4 waves (2x2 of 64x64).
// Writes per-row minima of s = wsq[h] - 2*dot at 16-column granularity.
__global__ __launch_bounds__(256) void phase1_mfma_kernel(
    const unsigned short* __restrict__ xhi, const unsigned short* __restrict__ xlo,
    const unsigned short* __restrict__ whi, const unsigned short* __restrict__ wlo,
    const float* __restrict__ wsq, float* __restrict__ gmin16 /*[B_][256]*/) {
  __shared__ unsigned short Ah[128 * 32], Al[128 * 32], Bh[128 * 32], Bl[128 * 32];
  const int tid = (int)threadIdx.x;
  const int wid = tid >> 6, lane = tid & 63;
  const int wr = wid >> 1, wc = wid & 1;
  const int rb = blockIdx.x, cb = blockIdx.y;
  const int row0 = rb * 128, col0 = cb * 128;

  f32x4 acc[4][4];
  #pragma unroll
  for (int i = 0; i < 4; ++i)
    #pragma unroll
    for (int j = 0; j < 4; ++j) acc[i][j] = (f32x4){0.f, 0.f, 0.f, 0.f};

  const int arow = wr * 64 + (lane & 15);
  const int brow = wc * 64 + (lane & 15);
  const int kf = (lane >> 4) * 16;    // byte offset of this lane's 8-bf16 k-group

  for (int kt = 0; kt < K_ / 32; ++kt) {
    __syncthreads();
    int kb = kt * 64;                 // byte offset into a 1024B bf16 row
    stage_tile(Ah, xhi, row0, kb, wid, lane);
    stage_tile(Al, xlo, row0, kb, wid, lane);
    stage_tile(Bh, whi, col0, kb, wid, lane);
    stage_tile(Bl, wlo, col0, kb, wid, lane);
    __syncthreads();

    bf16x8 ah[4], al[4];
    #pragma unroll
    for (int mf = 0; mf < 4; ++mf) {
      ah[mf] = lds_frag(Ah, arow + mf * 16, kf);
      al[mf] = lds_frag(Al, arow + mf * 16, kf);
    }
    #pragma unroll
    for (int nf = 0; nf < 4; ++nf) {
      bf16x8 bh = lds_frag(Bh, brow + nf * 16, kf);
      bf16x8 bl = lds_frag(Bl, brow + nf * 16, kf);
      #pragma unroll
      for (int mf = 0; mf < 4; ++mf) {
        acc[mf][nf] = __builtin_amdgcn_mfma_f32_16x16x32_bf16(ah[mf], bh, acc[mf][nf], 0, 0, 0);
        acc[mf][nf] = __builtin_amdgcn_mfma_f32_16x16x32_bf16(ah[mf], bl, acc[mf][nf], 0, 0, 0);
        acc[mf][nf] = __builtin_amdgcn_mfma_f32_16x16x32_bf16(al[mf], bh, acc[mf][nf], 0, 0, 0);
      }
    }
  }

  // Epilogue: s = wsq[col] - 2*acc; per-row min over each 16-col group.
  // D layout: col = lane&15, row = (lane>>4)*4 + reg  [m89-verified]
  #pragma unroll
  for (int nf = 0; nf < 4; ++nf) {
    int col = col0 + wc * 64 + nf * 16 + (lane & 15);
    float wq = wsq[col];
    int g = cb * 8 + wc * 4 + nf;
    #pragma unroll
    for (int mf = 0; mf < 4; ++mf) {
      int rowbase = row0 + wr * 64 + mf * 16 + (lane >> 4) * 4;
      #pragma unroll
      for (int r = 0; r < 4; ++r) {
        float m = wq - 2.0f * acc[mf][nf][r];
        #pragma unroll
        for (int off = 1; off < 16; off <<= 1) m = fminf(m, __shfl_xor(m, off));
        if ((lane & 15) == r) gmin16[(size_t)(rowbase + r) * 256 + g] = m;
      }
    }
  }
}

#define EPS_FLAG 0.0625f

// One block per row: find flagged 16-col groups, rescore exactly (BLAS-order
// FMA chain, proven bitwise vs reference), pick min (dist,idx) key, gather.
__global__ __launch_bounds__(256) void phase2_rescore_kernel(
    const float* __restrict__ gm /*[B_][256]*/, const float* __restrict__ x,
    const float* __restrict__ W, const float* __restrict__ xsq,
    const float* __restrict__ wsq, const float* __restrict__ GT,
    float* __restrict__ out) {
  const int b = blockIdx.x;
  const int tid = (int)threadIdx.x;
  __shared__ float xrow[K_];
  __shared__ float wmin[4];
  __shared__ unsigned long long bestkey;
  __shared__ int ngrp;
  __shared__ short grps[256];

  float v = gm[(size_t)b * 256 + tid];
  float m = v;
  #pragma unroll
  for (int off = 1; off < 64; off <<= 1) m = fminf(m, __shfl_xor(m, off));
  if ((tid & 63) == 0) wmin[tid >> 6] = m;
  if (tid == 0) { bestkey = 0xFFFFFFFFFFFFFFFFULL; ngrp = 0; }
  ((float2*)xrow)[tid] = ((const float2*)(x + (size_t)b * K_))[tid];
  __syncthreads();

  float gmin = fminf(fminf(wmin[0], wmin[1]), fminf(wmin[2], wmin[3]));
  float xq = xsq[b];
  if (v <= gmin + EPS_FLAG || v + xq <= EPS_FLAG) {
    int slot = atomicAdd(&ngrp, 1);
    grps[slot] = (short)tid;
  }
  __syncthreads();

  int n = ngrp;
  for (int q = tid >> 4; q < n; q += 16) {
    int h = (int)grps[q] * 16 + (tid & 15);
    const float* wr = W + (size_t)h * K_;
    float acc = 0.0f;
    for (int k = 0; k < K_; ++k) acc = fmaf(xrow[k], wr[k], acc);
    float t2 = xq - 2.0f * acc;
    float sq = t2 + wsq[h];
    float d = sqrtf(fmaxf(sq, 0.0f));
    unsigned long long key =
        ((unsigned long long)__float_as_uint(d) << 32) | (unsigned)h;
    atomicMin(&bestkey, key);
  }
  __syncthreads();

  unsigned h = (unsigned)(bestkey & 0xFFFFFFFFULL);
  ((float2*)(out + (size_t)b * O_))[tid] = ((const float2*)(GT + (size_t)h * O_))[tid];
  if (tid == 0) out[(size_t)B_ * O_ + b] = (float)h;
}

// ---------------------------------------------------------------------------
// Round-1 fallback path (exact f32 vector GEMM + argmin) — used if ws too small
// ---------------------------------------------------------------------------
#define BM 128
#define BN 128
#define BKK 16

__global__ void init_keys_kernel(unsigned long long* __restrict__ keys) {
  int i = blockIdx.x * blockDim.x + threadIdx.x;
  if (i < B_) keys[i] = 0xFFFFFFFFFFFFFFFFULL;
}

__global__ __launch_bounds__(256) void dist_argmin_kernel(
    const float* __restrict__ x, const float* __restrict__ W,
    const float* __restrict__ xsq, const float* __restrict__ wsq,
    unsigned long long* __restrict__ keys) {
  __shared__ float xs[BKK][BM + 4];
  __shared__ float wsh[BKK][BN + 4];
  const int row0 = blockIdx.x * BM;
  const int col0 = blockIdx.y * BN;
  const int tid = (int)threadIdx.x;
  const int tx = tid & 15, ty = tid >> 4;

  float acc[8][8];
  #pragma unroll
  for (int i = 0; i < 8; ++i)
    #pragma unroll
    for (int j = 0; j < 8; ++j) acc[i][j] = 0.0f;

  for (int kt = 0; kt < K_; kt += BKK) {
    #pragma unroll
    for (int l = 0; l < 2; ++l) {
      int e = tid + l * 256;
      int r = e >> 2, kq = e & 3;
      float4 v = *(const float4*)(x + (size_t)(row0 + r) * K_ + kt + kq * 4);
      xs[kq * 4 + 0][r] = v.x;
      xs[kq * 4 + 1][r] = v.y;
      xs[kq * 4 + 2][r] = v.z;
      xs[kq * 4 + 3][r] = v.w;
      float4 u = *(const float4*)(W + (size_t)(col0 + r) * K_ + kt + kq * 4);
      wsh[kq * 4 + 0][r] = u.x;
      wsh[kq * 4 + 1][r] = u.y;
      wsh[kq * 4 + 2][r] = u.z;
      wsh[kq * 4 + 3][r] = u.w;
    }
    __syncthreads();
    #pragma unroll
    for (int k = 0; k < BKK; ++k) {
      float4 a0 = *(const float4*)&xs[k][ty * 4];
      float4 a1 = *(const float4*)&xs[k][ty * 4 + 64];
      float4 b0 = *(const float4*)&wsh[k][tx * 4];
      float4 b1 = *(const float4*)&wsh[k][tx * 4 + 64];
      float ar[8] = {a0.x, a0.y, a0.z, a0.w, a1.x, a1.y, a1.z, a1.w};
      float br[8] = {b0.x, b0.y, b0.z, b0.w, b1.x, b1.y, b1.z, b1.w};
      #pragma unroll
      for (int i = 0; i < 8; ++i)
        #pragma unroll
        for (int j = 0; j < 8; ++j)
          acc[i][j] = fmaf(ar[i], br[j], acc[i][j]);
    }
    __syncthreads();
  }

  float xv[8], wv[8];
  int rowidx[8], colidx[8];
  #pragma unroll
  for (int i = 0; i < 8; ++i) {
    rowidx[i] = row0 + ty * 4 + (i & 3) + (i >> 2) * 64;
    xv[i] = xsq[rowidx[i]];
  }
  #pragma unroll
  for (int j = 0; j < 8; ++j) {
    colidx[j] = col0 + tx * 4 + (j & 3) + (j >> 2) * 64;
    wv[j] = wsq[colidx[j]];
  }
  #pragma unroll
  for (int i = 0; i < 8; ++i) {
    unsigned long long best = 0xFFFFFFFFFFFFFFFFULL;
    #pragma unroll
    for (int j = 0; j < 8; ++j) {
      float t2 = xv[i] - 2.0f * acc[i][j];
      float sq = t2 + wv[j];
      float d = sqrtf(fmaxf(sq, 0.0f));
      unsigned long long key =
          ((unsigned long long)__float_as_uint(d) << 32) | (unsigned)colidx[j];
      best = key < best ? key : best;
    }
    #pragma unroll
    for (int off = 1; off < 16; off <<= 1) {
      unsigned long long o = __shfl_xor(best, off, 16);
      best = o < best ? o : best;
    }
    if (tx == 0) atomicMin(&keys[rowidx[i]], best);
  }
}

__global__ void finalize_kernel(const unsigned long long* __restrict__ keys,
                                const float* __restrict__ GT,
                                const float* __restrict__ G,
                                float* __restrict__ out, int useGT) {
  int b = blockIdx.x;
  unsigned h = (unsigned)(keys[b] & 0xFFFFFFFFULL);
  if (threadIdx.x == 0) out[(size_t)B_ * O_ + b] = (float)h;
  if (useGT) {
    const float4* src = (const float4*)(GT + (size_t)h * O_);
    float4* dst = (float4*)(out + (size_t)b * O_);
    for (int i = threadIdx.x; i < O_ / 4; i += blockDim.x) dst[i] = src[i];
  } else {
    for (int o = threadIdx.x; o < O_; o += blockDim.x)
      out[(size_t)b * O_ + o] = G[(size_t)o * H_ + h];
  }
}

// ---------------------------------------------------------------------------
extern "C" void kernel_launch(void* const* d_in, const int* in_sizes, int n_in,
                              void* d_out, int out_size, void* d_ws, size_t ws_size,
                              hipStream_t stream) {
  const float* x = (const float*)d_in[0];
  const float* W = (const float*)d_in[1];
  const float* G = (const float*)d_in[2];
  float* out = (float*)d_out;
  char* ws = (char*)d_ws;

  // MFMA-path workspace layout
  size_t o_xsq = 0;                       // 64 KB
  size_t o_wsq = o_xsq + 65536;           // 16 KB
  size_t o_xhi = o_wsq + 16384;           // 16 MB
  size_t o_xlo = o_xhi + (size_t)B_ * K_ * 2;
  size_t o_whi = o_xlo + (size_t)B_ * K_ * 2;   // 4 MB
  size_t o_wlo = o_whi + (size_t)H_ * K_ * 2;
  size_t o_gm  = o_wlo + (size_t)H_ * K_ * 2;   // 16 MB
  size_t o_gt  = o_gm + (size_t)B_ * 256 * 4;   // 8 MB
  size_t need  = o_gt + (size_t)H_ * O_ * 4;

  if (ws_size >= need) {
    float* xsq = (float*)(ws + o_xsq);
    float* wsq = (float*)(ws + o_wsq);
    unsigned short* xhi = (unsigned short*)(ws + o_xhi);
    unsigned short* xlo = (unsigned short*)(ws + o_xlo);
    unsigned short* whi = (unsigned short*)(ws + o_whi);
    unsigned short* wlo = (unsigned short*)(ws + o_wlo);
    float* gm = (float*)(ws + o_gm);
    float* GT = (float*)(ws + o_gt);

    hipLaunchKernelGGL(rowsumsq_kernel, dim3(B_ / 256), dim3(256), 0, stream, x, xsq, B_);
    hipLaunchKernelGGL(rowsumsq_kernel, dim3(H_ / 256), dim3(256), 0, stream, W, wsq, H_);
    hipLaunchKernelGGL(convert_hilo_kernel, dim3(B_ * K_ / 4 / 256), dim3(256), 0, stream,
                       x, xhi, xlo, B_ * K_ / 4);
    hipLaunchKernelGGL(convert_hilo_kernel, dim3(H_ * K_ / 4 / 256), dim3(256), 0, stream,
                       W, whi, wlo, H_ * K_ / 4);
    hipLaunchKernelGGL(transposeG_kernel, dim3(H_ / 32, O_ / 32), dim3(32, 8), 0, stream,
                       G, GT);
    hipLaunchKernelGGL(phase1_mfma_kernel, dim3(B_ / 128, H_ / 128), dim3(256), 0, stream,
                       xhi, xlo, whi, wlo, wsq, gm);
    hipLaunchKernelGGL(phase2_rescore_kernel, dim3(B_), dim3(256), 0, stream,
                       gm, x, W, xsq, wsq, GT, out);
    return;
  }

  // Fallback: round-1 exact path
  unsigned long long* keys = (unsigned long long*)ws;
  float* xsq = (float*)(ws + 131072);
  float* wsq = (float*)(ws + 131072 + 65536);
  float* GT = (float*)(ws + 131072 + 65536 + 16384);
  size_t base = 131072 + 65536 + 16384;
  int useGT = ws_size >= base + (size_t)H_ * O_ * 4 ? 1 : 0;

  hipLaunchKernelGGL(init_keys_kernel, dim3(B_ / 256), dim3(256), 0, stream, keys);
  hipLaunchKernelGGL(rowsumsq_kernel, dim3(B_ / 256), dim3(256), 0, stream, x, xsq, B_);
  hipLaunchKernelGGL(rowsumsq_kernel, dim3(H_ / 256), dim3(256), 0, stream, W, wsq, H_);
  if (useGT)
    hipLaunchKernelGGL(transposeG_kernel, dim3(H_ / 32, O_ / 32), dim3(32, 8), 0, stream,
                       G, GT);
  hipLaunchKernelGGL(dist_argmin_kernel, dim3(B_ / BM, H_ / BN), dim3(256), 0, stream,
                     x, W, xsq, wsq, keys);
  hipLaunchKernelGGL(finalize_kernel, dim3(B_), dim3(128), 0, stream, keys, GT, G, out,
                     useGT);
}

// Round 3
// 314.564 us; speedup vs baseline: 2.7168x; 1.5224x over previous
//
#include <hip/hip_runtime.h>
#include <cstdint>
#include <cstddef>

#define B_ 16384
#define K_ 512
#define H_ 4096
#define O_ 512

typedef __attribute__((ext_vector_type(4))) float f32x4;
typedef __attribute__((ext_vector_type(8))) short bf16x8;

// ---------------------------------------------------------------------------
// Exact helpers (bitwise vs numpy reference — proven in rounds 1-2)
// ---------------------------------------------------------------------------
__device__ inline unsigned short f32_to_bf16_rne(float f) {
  unsigned u = __float_as_uint(f);
  unsigned r = (u + 0x7fffu + ((u >> 16) & 1u)) >> 16;
  return (unsigned short)r;
}

__device__ float np_pairwise_sumsq512(const float* __restrict__ a) {
  float s[4];
  #pragma unroll
  for (int blk = 0; blk < 4; ++blk) {
    const float* p = a + blk * 128;
    float r[8];
    #pragma unroll
    for (int j = 0; j < 8; ++j) r[j] = __fmul_rn(p[j], p[j]);
    for (int i = 8; i < 128; i += 8) {
      #pragma unroll
      for (int j = 0; j < 8; ++j) r[j] = __fadd_rn(r[j], __fmul_rn(p[i + j], p[i + j]));
    }
    s[blk] = __fadd_rn(__fadd_rn(__fadd_rn(r[0], r[1]), __fadd_rn(r[2], r[3])),
                       __fadd_rn(__fadd_rn(r[4], r[5]), __fadd_rn(r[6], r[7])));
  }
  return __fadd_rn(__fadd_rn(s[0], s[1]), __fadd_rn(s[2], s[3]));
}

// Fused: coalesced load of 8 rows -> LDS; emit bf16(hi) coalesced; compute
// numpy-pairwise-order sumsq with 32 lanes/row (8 indep chains x 4 blocks,
// exact shfl combine tree). Bitwise-identical to np_pairwise_sumsq512.
__global__ __launch_bounds__(256) void prep_rows_kernel(
    const float* __restrict__ src, unsigned short* __restrict__ hi,
    float* __restrict__ sumsq, int nrows) {
  __shared__ float buf[8 * 512];
  const int r0 = blockIdx.x * 8;
  const int tid = (int)threadIdx.x;

  #pragma unroll
  for (int it = 0; it < 4; ++it) {
    int i = tid + it * 256;  // 0..1023 float4s
    float4 v = ((const float4*)(src + (size_t)r0 * K_))[i];
    ((float4*)buf)[i] = v;
    ushort4 h;
    h.x = f32_to_bf16_rne(v.x);
    h.y = f32_to_bf16_rne(v.y);
    h.z = f32_to_bf16_rne(v.z);
    h.w = f32_to_bf16_rne(v.w);
    ((ushort4*)(hi + (size_t)r0 * K_))[i] = h;
  }
  __syncthreads();

  const int row = tid >> 5, l = tid & 31, blk = l >> 3, j = l & 7;
  const float* p = buf + row * 512 + blk * 128;
  float r = __fmul_rn(p[j], p[j]);
  #pragma unroll
  for (int i = 8; i < 128; i += 8) r = __fadd_rn(r, __fmul_rn(p[i + j], p[i + j]));
  // combine j (bits 0..2): lane j=0 ends with ((r0+r1)+(r2+r3))+((r4+r5)+(r6+r7))
  r = __fadd_rn(r, __shfl_xor(r, 1));
  r = __fadd_rn(r, __shfl_xor(r, 2));
  r = __fadd_rn(r, __shfl_xor(r, 4));
  // combine blk (bits 3..4): lane l=0 ends with (s0+s1)+(s2+s3)... exact order
  r = __fadd_rn(r, __shfl_xor(r, 8));
  r = __fadd_rn(r, __shfl_xor(r, 16));
  if (l == 0 && r0 + row < nrows) sumsq[r0 + row] = r;
}

__global__ void rowsumsq_kernel(const float* __restrict__ src, float* __restrict__ dst,
                                int nrows) {
  int r = blockIdx.x * blockDim.x + threadIdx.x;
  if (r < nrows) dst[r] = np_pairwise_sumsq512(src + (size_t)r * K_);
}

// G [O_][H_] -> GT [H_][O_]
__global__ void transposeG_kernel(const float* __restrict__ G, float* __restrict__ GT) {
  __shared__ float t[32][33];
  int h0 = blockIdx.x * 32, o0 = blockIdx.y * 32;
  for (int i = threadIdx.y; i < 32; i += 8)
    t[i][threadIdx.x] = G[(size_t)(o0 + i) * H_ + h0 + threadIdx.x];
  __syncthreads();
  for (int i = threadIdx.y; i < 32; i += 8)
    GT[(size_t)(h0 + i) * O_ + o0 + threadIdx.x] = t[threadIdx.x][i];
}

// ---------------------------------------------------------------------------
// Phase 1: single-product hi*hi bf16 MFMA; per-row minima at 16-col granularity
// ---------------------------------------------------------------------------
__device__ inline void stage_tile(unsigned short* lds, const unsigned short* src,
                                  int row0, int kb, int wid, int lane) {
  #pragma unroll
  for (int j = 0; j < 2; ++j) {
    int chunk = wid + j * 4;          // 8 x 1KB chunks = [128][32]bf16 tile
    int e = chunk * 64 + lane;        // 16B-unit index, 0..511
    int row = e >> 2, kc = e & 3;
    const char* g = (const char*)src + (size_t)(row0 + row) * (K_ * 2) + kb + kc * 16;
    char* l = (char*)lds + chunk * 1024;
    __builtin_amdgcn_global_load_lds((const __attribute__((address_space(1))) void*)g,
                                     (__attribute__((address_space(3))) void*)l,
                                     16, 0, 0);
  }
}

__device__ inline bf16x8 lds_frag(const unsigned short* lds, int row, int kbyte) {
  return *(const bf16x8*)((const char*)lds + row * 64 + kbyte);
}

__global__ __launch_bounds__(256) void phase1_mfma_kernel(
    const unsigned short* __restrict__ xhi, const unsigned short* __restrict__ whi,
    const float* __restrict__ wsq, float* __restrict__ gmin16 /*[B_][256]*/) {
  __shared__ unsigned short Ah[128 * 32], Bh[128 * 32];
  const int tid = (int)threadIdx.x;
  const int wid = tid >> 6, lane = tid & 63;
  const int wr = wid >> 1, wc = wid & 1;
  const int rb = blockIdx.x, cb = blockIdx.y;
  const int row0 = rb * 128, col0 = cb * 128;

  f32x4 acc[4][4];
  #pragma unroll
  for (int i = 0; i < 4; ++i)
    #pragma unroll
    for (int j = 0; j < 4; ++j) acc[i][j] = (f32x4){0.f, 0.f, 0.f, 0.f};

  const int arow = wr * 64 + (lane & 15);
  const int brow = wc * 64 + (lane & 15);
  const int kf = (lane >> 4) * 16;    // byte offset of this lane's 8-bf16 k-group

  for (int kt = 0; kt < K_ / 32; ++kt) {
    __syncthreads();
    int kb = kt * 64;                 // byte offset into 1024B bf16 row
    stage_tile(Ah, xhi, row0, kb, wid, lane);
    stage_tile(Bh, whi, col0, kb, wid, lane);
    __syncthreads();

    bf16x8 ah[4];
    #pragma unroll
    for (int mf = 0; mf < 4; ++mf) ah[mf] = lds_frag(Ah, arow + mf * 16, kf);
    #pragma unroll
    for (int nf = 0; nf < 4; ++nf) {
      bf16x8 bh = lds_frag(Bh, brow + nf * 16, kf);
      #pragma unroll
      for (int mf = 0; mf < 4; ++mf)
        acc[mf][nf] = __builtin_amdgcn_mfma_f32_16x16x32_bf16(ah[mf], bh, acc[mf][nf], 0, 0, 0);
    }
  }

  // s_approx = wsq[col] - 2*dot; per-row min over each 16-col group.
  // D layout: col = lane&15, row = (lane>>4)*4 + reg  [m89-verified]
  #pragma unroll
  for (int nf = 0; nf < 4; ++nf) {
    int col = col0 + wc * 64 + nf * 16 + (lane & 15);
    float wq = wsq[col];
    int g = cb * 8 + wc * 4 + nf;
    #pragma unroll
    for (int mf = 0; mf < 4; ++mf) {
      int rowbase = row0 + wr * 64 + mf * 16 + (lane >> 4) * 4;
      #pragma unroll
      for (int r = 0; r < 4; ++r) {
        float m = wq - 2.0f * acc[mf][nf][r];
        #pragma unroll
        for (int off = 1; off < 16; off <<= 1) m = fminf(m, __shfl_xor(m, off));
        if ((lane & 15) == r) gmin16[(size_t)(rowbase + r) * 256 + g] = m;
      }
    }
  }
}

#define EPS_FLAG 0.125f

// One block per row: flag candidate groups, rescore exactly (BLAS-order FMA
// chain, bitwise vs reference), pick min (dist_bits, h) key, fused gather.
__global__ __launch_bounds__(256) void phase2_rescore_kernel(
    const float* __restrict__ gm /*[B_][256]*/, const float* __restrict__ x,
    const float* __restrict__ W, const float* __restrict__ xsq,
    const float* __restrict__ wsq, const float* __restrict__ GT,
    float* __restrict__ out) {
  const int b = blockIdx.x;
  const int tid = (int)threadIdx.x;
  __shared__ float xrow[K_];
  __shared__ float wmin[4];
  __shared__ unsigned long long bestkey;
  __shared__ int ngrp;
  __shared__ short grps[256];

  float v = gm[(size_t)b * 256 + tid];
  float m = v;
  #pragma unroll
  for (int off = 1; off < 64; off <<= 1) m = fminf(m, __shfl_xor(m, off));
  if ((tid & 63) == 0) wmin[tid >> 6] = m;
  if (tid == 0) { bestkey = 0xFFFFFFFFFFFFFFFFULL; ngrp = 0; }
  ((float2*)xrow)[tid] = ((const float2*)(x + (size_t)b * K_))[tid];
  __syncthreads();

  float gmin = fminf(fminf(wmin[0], wmin[1]), fminf(wmin[2], wmin[3]));
  float xq = xsq[b];
  if (v <= gmin + EPS_FLAG || v + xq <= EPS_FLAG) {
    int slot = atomicAdd(&ngrp, 1);
    grps[slot] = (short)tid;
  }
  __syncthreads();

  int n = ngrp;
  for (int q = tid >> 4; q < n; q += 16) {
    int h = (int)grps[q] * 16 + (tid & 15);
    const float* wr = W + (size_t)h * K_;
    float acc = 0.0f;
    for (int k = 0; k < K_; ++k) acc = fmaf(xrow[k], wr[k], acc);
    float t2 = xq - 2.0f * acc;
    float sq = t2 + wsq[h];
    float d = sqrtf(fmaxf(sq, 0.0f));
    unsigned long long key =
        ((unsigned long long)__float_as_uint(d) << 32) | (unsigned)h;
    atomicMin(&bestkey, key);
  }
  __syncthreads();

  unsigned h = (unsigned)(bestkey & 0xFFFFFFFFULL);
  ((float2*)(out + (size_t)b * O_))[tid] = ((const float2*)(GT + (size_t)h * O_))[tid];
  if (tid == 0) out[(size_t)B_ * O_ + b] = (float)h;
}

// ---------------------------------------------------------------------------
// Round-1 fallback (exact f32 vector GEMM + argmin) — used only if ws too small
// ---------------------------------------------------------------------------
#define BM 128
#define BN 128
#define BKK 16

__global__ void init_keys_kernel(unsigned long long* __restrict__ keys) {
  int i = blockIdx.x * blockDim.x + threadIdx.x;
  if (i < B_) keys[i] = 0xFFFFFFFFFFFFFFFFULL;
}

__global__ __launch_bounds__(256) void dist_argmin_kernel(
    const float* __restrict__ x, const float* __restrict__ W,
    const float* __restrict__ xsq, const float* __restrict__ wsq,
    unsigned long long* __restrict__ keys) {
  __shared__ float xs[BKK][BM + 4];
  __shared__ float wsh[BKK][BN + 4];
  const int row0 = blockIdx.x * BM;
  const int col0 = blockIdx.y * BN;
  const int tid = (int)threadIdx.x;
  const int tx = tid & 15, ty = tid >> 4;

  float acc[8][8];
  #pragma unroll
  for (int i = 0; i < 8; ++i)
    #pragma unroll
    for (int j = 0; j < 8; ++j) acc[i][j] = 0.0f;

  for (int kt = 0; kt < K_; kt += BKK) {
    #pragma unroll
    for (int l = 0; l < 2; ++l) {
      int e = tid + l * 256;
      int r = e >> 2, kq = e & 3;
      float4 v = *(const float4*)(x + (size_t)(row0 + r) * K_ + kt + kq * 4);
      xs[kq * 4 + 0][r] = v.x;
      xs[kq * 4 + 1][r] = v.y;
      xs[kq * 4 + 2][r] = v.z;
      xs[kq * 4 + 3][r] = v.w;
      float4 u = *(const float4*)(W + (size_t)(col0 + r) * K_ + kt + kq * 4);
      wsh[kq * 4 + 0][r] = u.x;
      wsh[kq * 4 + 1][r] = u.y;
      wsh[kq * 4 + 2][r] = u.z;
      wsh[kq * 4 + 3][r] = u.w;
    }
    __syncthreads();
    #pragma unroll
    for (int k = 0; k < BKK; ++k) {
      float4 a0 = *(const float4*)&xs[k][ty * 4];
      float4 a1 = *(const float4*)&xs[k][ty * 4 + 64];
      float4 b0 = *(const float4*)&wsh[k][tx * 4];
      float4 b1 = *(const float4*)&wsh[k][tx * 4 + 64];
      float ar[8] = {a0.x, a0.y, a0.z, a0.w, a1.x, a1.y, a1.z, a1.w};
      float br[8] = {b0.x, b0.y, b0.z, b0.w, b1.x, b1.y, b1.z, b1.w};
      #pragma unroll
      for (int i = 0; i < 8; ++i)
        #pragma unroll
        for (int j = 0; j < 8; ++j)
          acc[i][j] = fmaf(ar[i], br[j], acc[i][j]);
    }
    __syncthreads();
  }

  float xv[8], wv[8];
  int rowidx[8], colidx[8];
  #pragma unroll
  for (int i = 0; i < 8; ++i) {
    rowidx[i] = row0 + ty * 4 + (i & 3) + (i >> 2) * 64;
    xv[i] = xsq[rowidx[i]];
  }
  #pragma unroll
  for (int j = 0; j < 8; ++j) {
    colidx[j] = col0 + tx * 4 + (j & 3) + (j >> 2) * 64;
    wv[j] = wsq[colidx[j]];
  }
  #pragma unroll
  for (int i = 0; i < 8; ++i) {
    unsigned long long best = 0xFFFFFFFFFFFFFFFFULL;
    #pragma unroll
    for (int j = 0; j < 8; ++j) {
      float t2 = xv[i] - 2.0f * acc[i][j];
      float sq = t2 + wv[j];
      float d = sqrtf(fmaxf(sq, 0.0f));
      unsigned long long key =
          ((unsigned long long)__float_as_uint(d) << 32) | (unsigned)colidx[j];
      best = key < best ? key : best;
    }
    #pragma unroll
    for (int off = 1; off < 16; off <<= 1) {
      unsigned long long o = __shfl_xor(best, off, 16);
      best = o < best ? o : best;
    }
    if (tx == 0) atomicMin(&keys[rowidx[i]], best);
  }
}

__global__ void finalize_kernel(const unsigned long long* __restrict__ keys,
                                const float* __restrict__ GT,
                                const float* __restrict__ G,
                                float* __restrict__ out, int useGT) {
  int b = blockIdx.x;
  unsigned h = (unsigned)(keys[b] & 0xFFFFFFFFULL);
  if (threadIdx.x == 0) out[(size_t)B_ * O_ + b] = (float)h;
  if (useGT) {
    const float4* src = (const float4*)(GT + (size_t)h * O_);
    float4* dst = (float4*)(out + (size_t)b * O_);
    for (int i = threadIdx.x; i < O_ / 4; i += blockDim.x) dst[i] = src[i];
  } else {
    for (int o = threadIdx.x; o < O_; o += blockDim.x)
      out[(size_t)b * O_ + o] = G[(size_t)o * H_ + h];
  }
}

// ---------------------------------------------------------------------------
extern "C" void kernel_launch(void* const* d_in, const int* in_sizes, int n_in,
                              void* d_out, int out_size, void* d_ws, size_t ws_size,
                              hipStream_t stream) {
  const float* x = (const float*)d_in[0];
  const float* W = (const float*)d_in[1];
  const float* G = (const float*)d_in[2];
  float* out = (float*)d_out;
  char* ws = (char*)d_ws;

  // MFMA-path workspace layout
  size_t o_xsq = 0;                             // 64 KB
  size_t o_wsq = o_xsq + 65536;                 // 16 KB
  size_t o_xhi = o_wsq + 16384;                 // 16 MB
  size_t o_whi = o_xhi + (size_t)B_ * K_ * 2;   // 4 MB
  size_t o_gm  = o_whi + (size_t)H_ * K_ * 2;   // 16 MB
  size_t o_gt  = o_gm + (size_t)B_ * 256 * 4;   // 8 MB
  size_t need  = o_gt + (size_t)H_ * O_ * 4;

  if (ws_size >= need) {
    float* xsq = (float*)(ws + o_xsq);
    float* wsq = (float*)(ws + o_wsq);
    unsigned short* xhi = (unsigned short*)(ws + o_xhi);
    unsigned short* whi = (unsigned short*)(ws + o_whi);
    float* gm = (float*)(ws + o_gm);
    float* GT = (float*)(ws + o_gt);

    hipLaunchKernelGGL(prep_rows_kernel, dim3(B_ / 8), dim3(256), 0, stream,
                       x, xhi, xsq, B_);
    hipLaunchKernelGGL(prep_rows_kernel, dim3(H_ / 8), dim3(256), 0, stream,
                       W, whi, wsq, H_);
    hipLaunchKernelGGL(transposeG_kernel, dim3(H_ / 32, O_ / 32), dim3(32, 8), 0, stream,
                       G, GT);
    hipLaunchKernelGGL(phase1_mfma_kernel, dim3(B_ / 128, H_ / 128), dim3(256), 0, stream,
                       xhi, whi, wsq, gm);
    hipLaunchKernelGGL(phase2_rescore_kernel, dim3(B_), dim3(256), 0, stream,
                       gm, x, W, xsq, wsq, GT, out);
    return;
  }

  // Fallback: round-1 exact path
  unsigned long long* keys = (unsigned long long*)ws;
  float* xsq = (float*)(ws + 131072);
  float* wsq = (float*)(ws + 131072 + 65536);
  float* GT = (float*)(ws + 131072 + 65536 + 16384);
  size_t base = 131072 + 65536 + 16384;
  int useGT = ws_size >= base + (size_t)H_ * O_ * 4 ? 1 : 0;

  hipLaunchKernelGGL(init_keys_kernel, dim3(B_ / 256), dim3(256), 0, stream, keys);
  hipLaunchKernelGGL(rowsumsq_kernel, dim3(B_ / 256), dim3(256), 0, stream, x, xsq, B_);
  hipLaunchKernelGGL(rowsumsq_kernel, dim3(H_ / 256), dim3(256), 0, stream, W, wsq, H_);
  if (useGT)
    hipLaunchKernelGGL(transposeG_kernel, dim3(H_ / 32, O_ / 32), dim3(32, 8), 0, stream,
                       G, GT);
  hipLaunchKernelGGL(dist_argmin_kernel, dim3(B_ / BM, H_ / BN), dim3(256), 0, stream,
                     x, W, xsq, wsq, keys);
  hipLaunchKernelGGL(finalize_kernel, dim3(B_), dim3(128), 0, stream, keys, GT, G, out,
                     useGT);
}